// Round 7
// baseline (304.257 us; speedup 1.0000x reference)
//
#include <hip/hip_runtime.h>
#include <stdint.h>

// ---------------- types ----------------
typedef short shortx8 __attribute__((ext_vector_type(8)));
typedef float floatx4 __attribute__((ext_vector_type(4)));

#define T_LEN 2048
#define BATCH 16
#define DMODEL 512
#define HDIM 512
#define M_ROWS (T_LEN * BATCH)          // 32768
#define NCHUNK 32
#define LCHUNK 64                        // T per chunk
#define NCHAIN (BATCH * HDIM)            // 8192
#define Y_ELEMS (M_ROWS * DMODEL)        // 16777216

// ---------------- helpers ----------------
__device__ __forceinline__ unsigned short f2bf(float f) {
    union { float f; unsigned u; } v; v.f = f;
    unsigned r = (v.u + 0x7FFFu + ((v.u >> 16) & 1u)) >> 16;
    return (unsigned short)r;
}
__device__ __forceinline__ float bf2f(unsigned short u) {
    union { unsigned u; float f; } v; v.u = ((unsigned)u) << 16;
    return v.f;
}

// ---------------- merged prep + operand conversion + x cast ----------------
// blocks 0..16383:      x fp32 -> bf16 cast (float4/ushort4 vectorized)
// blocks 16384..20479:  Bs/C2 conversion (interleaved cols: n=2h -> re, 2h+1 -> im)
// block 20480:          per-channel lam, lam^64 (double precision)
__global__ void conv_all(const float4* __restrict__ x4, unsigned short* __restrict__ xb,
                         const float* __restrict__ B_re, const float* __restrict__ B_im,
                         const float* __restrict__ nu_log, const float* __restrict__ th_log,
                         const float* __restrict__ C_re, const float* __restrict__ C_im,
                         unsigned short* __restrict__ Bs, unsigned short* __restrict__ C2,
                         float* lam_re, float* lam_im, float* l64_re, float* l64_im) {
    int bid = blockIdx.x;
    int tid = threadIdx.x;
    if (bid < 16384) {
        int i = bid * 256 + tid;         // 0 .. Y_ELEMS/4-1
        float4 v = x4[i];
        ushort4 u;
        u.x = f2bf(v.x); u.y = f2bf(v.y); u.z = f2bf(v.z); u.w = f2bf(v.w);
        *(ushort4*)(xb + (size_t)i * 4) = u;
    } else if (bid < 20480) {
        int idx = (bid - 16384) * 256 + tid;   // 0 .. 1M-1
        if (idx < 524288) {
            int n = idx >> 9;            // row 0..1023
            int d = idx & 511;
            int h = n >> 1;
            float g = sqrtf(1.0f - expf(-2.0f * expf(nu_log[h])));
            float v = ((n & 1) ? B_im[h * DMODEL + d] : B_re[h * DMODEL + d]) * g;
            Bs[idx] = f2bf(v);
        } else {
            int i2 = idx - 524288;
            int d = i2 >> 10;            // /1024
            int k = i2 & 1023;
            int h = k >> 1;
            float v = (k & 1) ? -C_im[d * HDIM + h] : C_re[d * HDIM + h];
            C2[i2] = f2bf(v);
        }
    } else {
        for (int h = tid; h < HDIM; h += 256) {
            double nu  = exp((double)nu_log[h]);
            double th  = exp((double)th_log[h]);
            double mag = exp(-nu);
            double lre = mag * cos(th), lim = mag * sin(th);
            double zr = lre, zi = lim;
            for (int i = 0; i < 6; ++i) { double nr = zr*zr - zi*zi; zi = 2.0*zr*zi; zr = nr; }
            lam_re[h] = (float)lre; lam_im[h] = (float)lim;
            l64_re[h] = (float)zr;  l64_im[h] = (float)zi;
        }
    }
}

// ---------------- NT GEMM, 128x128 tile, BK=64, bf16 MFMA 16x16x32 ----------------
// (round-0/3 kernel; launch_bounds bumped to 5 blocks/CU: LDS 32KiB x 5 = 160KiB
//  exactly fills the CU pool; VGPR=64 far under the 5-wave cap.  If HW can't
//  fit 5, occupancy silently stays 4 -> no regression.)
// A: M x K row-major bf16.  Bmat: N x K row-major bf16.  D[m][n] = sum_k A[m][k]*Bmat[n][k]
// LDS tiles 128x64 with XOR-swizzled 16B column chunks (c16 ^= r&7).
// MODE 0: OutB[m*N+n] = bf16(acc)
// MODE 1: OutF[m*N+n] = acc + Dv[n]*bf2f(Xb[m*N+n])
template <int MODE>
__global__ __launch_bounds__(256, 5) void gemm_nt(const unsigned short* __restrict__ A,
                                                  const unsigned short* __restrict__ Bmat,
                                                  const int K, const int N, const int lgNB,
                                                  unsigned short* __restrict__ OutB,
                                                  float* __restrict__ OutF,
                                                  const float* __restrict__ Dv,
                                                  const unsigned short* __restrict__ Xb) {
    __shared__ unsigned short As[128 * 64];
    __shared__ unsigned short Bs[128 * 64];
    const int L = blockIdx.x;
    const int xcd = L & 7;
    const int slot = L >> 3;
    const int bn = slot & ((1 << lgNB) - 1);
    const int bm = xcd * 32 + (slot >> lgNB);
    const int tid = threadIdx.x;
    const int wv = tid >> 6, lane = tid & 63;
    const int wr = wv >> 1, wc = wv & 1;
    const int lrow = lane & 15, qq = lane >> 4;
    floatx4 acc[4][4] = {};

    const size_t rowA = (size_t)bm * 128, rowB = (size_t)bn * 128;
    for (int k0 = 0; k0 < K; k0 += 64) {
        #pragma unroll
        for (int j = 0; j < 4; ++j) {
            int ch  = j * 256 + wv * 64 + lane;            // 0..1023
            int r   = ch >> 3;                             // row 0..127
            int c16 = ch & 7;                              // LDS 16B-col
            int g16 = c16 ^ (r & 7);                       // swizzled global 16B-col
            const unsigned short* ga = A    + (rowA + r) * (size_t)K + (k0 + g16 * 8);
            const unsigned short* gb = Bmat + (rowB + r) * (size_t)K + (k0 + g16 * 8);
            unsigned short* la = As + (size_t)(j * 256 + wv * 64) * 8;   // wave-uniform base
            unsigned short* lb = Bs + (size_t)(j * 256 + wv * 64) * 8;
            __builtin_amdgcn_global_load_lds((const __attribute__((address_space(1))) void*)ga,
                                             (__attribute__((address_space(3))) void*)la, 16, 0, 0);
            __builtin_amdgcn_global_load_lds((const __attribute__((address_space(1))) void*)gb,
                                             (__attribute__((address_space(3))) void*)lb, 16, 0, 0);
        }
        __syncthreads();
        #pragma unroll
        for (int s = 0; s < 2; ++s) {                      // two k-substeps of 32
            shortx8 af[4], bf[4];
            #pragma unroll
            for (int mi = 0; mi < 4; ++mi) {
                int row = wr * 64 + mi * 16 + lrow;
                int c16 = (s * 4 + qq) ^ (row & 7);
                af[mi] = *(const shortx8*)&As[row * 64 + c16 * 8];
            }
            #pragma unroll
            for (int ni = 0; ni < 4; ++ni) {
                int row = wc * 64 + ni * 16 + lrow;
                int c16 = (s * 4 + qq) ^ (row & 7);
                bf[ni] = *(const shortx8*)&Bs[row * 64 + c16 * 8];
            }
            #pragma unroll
            for (int mi = 0; mi < 4; ++mi)
                #pragma unroll
                for (int ni = 0; ni < 4; ++ni)
                    acc[mi][ni] = __builtin_amdgcn_mfma_f32_16x16x32_bf16(af[mi], bf[ni], acc[mi][ni], 0, 0, 0);
        }
        __syncthreads();
    }

    // epilogue: D row = qq*4 + r, col = lrow   (m89/m91-verified C/D mapping)
    #pragma unroll
    for (int mi = 0; mi < 4; ++mi) {
        int mbase = bm * 128 + wr * 64 + mi * 16 + qq * 4;
        #pragma unroll
        for (int ni = 0; ni < 4; ++ni) {
            int n = bn * 128 + wc * 64 + ni * 16 + lrow;
            if (MODE == 0) {
                #pragma unroll
                for (int r = 0; r < 4; ++r)
                    OutB[(size_t)(mbase + r) * N + n] = f2bf(acc[mi][ni][r]);
            } else {
                float dv = Dv[n];
                #pragma unroll
                for (int r = 0; r < 4; ++r) {
                    size_t idx = (size_t)(mbase + r) * N + n;
                    OutF[idx] = acc[mi][ni][r] + dv * bf2f(Xb[idx]);
                }
            }
        }
    }
}

// ---------------- scan pass 1: per-chunk partial (zero init), 1 channel/thread ----
// Interleaved Bu layout: channel h of row m lives at shorts (2h, 2h+1) ->
// one 4B load per step yields (re,im).  Chunk 31's partial is never consumed
// by scan_apply (carries only for k < chunk) -> grid covers chunks 0..30.
__global__ void scan_partial(const unsigned short* __restrict__ Bu,
                             const float* __restrict__ lam_re, const float* __restrict__ lam_im,
                             float2* __restrict__ car) {
    int gid = blockIdx.x * blockDim.x + threadIdx.x;     // 0 .. 31*8192-1
    int chunk = gid >> 13;           // block-uniform (8192 = 32 blocks of 256)
    int idx = gid & 8191;            // chain = b*512 + h
    int b = idx >> 9, h = idx & 511;
    float lr = lam_re[h], li = lam_im[h];
    float vr = 0.f, vi = 0.f;
    const unsigned short* p = Bu + (size_t)chunk * LCHUNK * BATCH * 1024 + (size_t)b * 1024 + 2 * h;
    #pragma unroll 4
    for (int j = 0; j < LCHUNK; ++j) {
        unsigned w = *(const unsigned*)p;
        float br = bf2f((unsigned short)w), bi = bf2f((unsigned short)(w >> 16));
        float nr = lr * vr - li * vi + br;
        float ni = lr * vi + li * vr + bi;
        vr = nr; vi = ni;
        p += BATCH * 1024;
    }
    car[chunk * NCHAIN + idx] = make_float2(vr, vi);
}

// ---------------- scan pass 2 (fused combine+apply), 1 channel/thread ----------
__global__ void scan_apply(unsigned short* __restrict__ Bu,
                           const float* __restrict__ lam_re, const float* __restrict__ lam_im,
                           const float* __restrict__ l64_re, const float* __restrict__ l64_im,
                           const float* __restrict__ h0_re, const float* __restrict__ h0_im,
                           const float2* __restrict__ car,
                           float* __restrict__ out_final, int interleave) {
    int gid = blockIdx.x * blockDim.x + threadIdx.x;
    int chunk = gid >> 13;           // block-uniform
    int idx = gid & 8191;            // chain = b*512 + h
    int b = idx >> 9, h = idx & 511;
    // carry-in: h0 advanced through preceding chunks via lam^64
    float Lr = l64_re[h], Li = l64_im[h];
    float vr = h0_re[idx], vi = h0_im[idx];
    for (int k = 0; k < chunk; ++k) {
        float2 cv = car[k * NCHAIN + idx];
        float nr = Lr * vr - Li * vi + cv.x;
        float ni = Lr * vi + Li * vr + cv.y;
        vr = nr; vi = ni;
    }
    // main 64-step streaming recurrence, h overwrites Bu in-place
    float lr = lam_re[h], li = lam_im[h];
    unsigned short* p = Bu + (size_t)chunk * LCHUNK * BATCH * 1024 + (size_t)b * 1024 + 2 * h;
    #pragma unroll 4
    for (int j = 0; j < LCHUNK; ++j) {
        unsigned w = *(const unsigned*)p;
        float br = bf2f((unsigned short)w), bi = bf2f((unsigned short)(w >> 16));
        float nr = lr * vr - li * vi + br;
        float ni = lr * vi + li * vr + bi;
        vr = nr; vi = ni;
        *(unsigned*)p = (unsigned)f2bf(vr) | ((unsigned)f2bf(vi) << 16);
        p += BATCH * 1024;
    }
    if (chunk == NCHUNK - 1) {       // final_state = h[T-1]
        if (interleave) {
            out_final[2 * idx]     = vr;
            out_final[2 * idx + 1] = vi;
        } else {
            out_final[idx] = vr;
        }
    }
}

// ---------------- launch ----------------
extern "C" void kernel_launch(void* const* d_in, const int* in_sizes, int n_in,
                              void* d_out, int out_size, void* d_ws, size_t ws_size,
                              hipStream_t stream) {
    const float* x        = (const float*)d_in[0];
    const float* h0_re    = (const float*)d_in[1];
    const float* h0_im    = (const float*)d_in[2];
    const float* nu_log   = (const float*)d_in[3];
    const float* theta_lg = (const float*)d_in[4];
    const float* B_re     = (const float*)d_in[5];
    const float* B_im     = (const float*)d_in[6];
    const float* C_re     = (const float*)d_in[7];
    const float* C_im     = (const float*)d_in[8];
    const float* D_vec    = (const float*)d_in[9];

    // workspace layout (~105 MB total)
    char* ws = (char*)d_ws;
    unsigned short* BuH  = (unsigned short*)(ws + 0);              // 64 MB  (M x 1024 bf16): Bu, then h in-place
    unsigned short* xb   = (unsigned short*)(ws + 67108864);       // 32 MB  (M x 512 bf16)
    unsigned short* Bs   = (unsigned short*)(ws + 100663296);      // 1 MB   (1024 x 512 bf16)
    unsigned short* C2   = (unsigned short*)(ws + 101711872);      // 1 MB   (512 x 1024 bf16)
    float2* car          = (float2*)(ws + 102760448);              // 2 MB   (32 x 8192 float2)
    float* lam_re        = (float*)(ws + 104857600);
    float* lam_im        = (float*)(ws + 104859648);
    float* l64_re        = (float*)(ws + 104861696);
    float* l64_im        = (float*)(ws + 104863744);

    // adaptive d_out layout: out_size = Y_ELEMS + {16384 interleaved | 8192 real-only}
    int fs_elems = out_size - Y_ELEMS;
    int interleave = (fs_elems == 8192) ? 0 : 1;
    if (fs_elems != 8192) fs_elems = 16384;
    float* out_final = (float*)d_out;
    float* y_out     = (float*)d_out + fs_elems;

    // 1. merged x-cast + operand conversions + channel constants (one launch)
    conv_all<<<20481, 256, 0, stream>>>((const float4*)x, xb,
                                        B_re, B_im, nu_log, theta_lg, C_re, C_im,
                                        Bs, C2, lam_re, lam_im, l64_re, l64_im);
    // 2. GEMM1: Bu = xb (M x 512) . Bs^T (1024 x 512) -> M x 1024 bf16 (interleaved cols)
    gemm_nt<0><<<2048, 256, 0, stream>>>(xb, Bs, DMODEL, 1024, 3, BuH, nullptr, nullptr, nullptr);
    // 3. chunked scan over T (partial for chunks 0..30 -> fused prefix+apply in-place)
    scan_partial<<<((NCHUNK - 1) * NCHAIN) / 256, 256, 0, stream>>>(BuH, lam_re, lam_im, car);
    scan_apply<<<(NCHUNK * NCHAIN) / 256, 256, 0, stream>>>(BuH, lam_re, lam_im, l64_re, l64_im,
                                                            h0_re, h0_im, car,
                                                            out_final, interleave);
    // 4. GEMM2: y = h (M x 1024) . C2^T (512 x 1024) + Dv*xb -> M x 512 fp32
    gemm_nt<1><<<1024, 256, 0, stream>>>(BuH, C2, 1024, 512, 2, nullptr, y_out, D_vec, xb);
}

// Round 8
// 258.467 us; speedup vs baseline: 1.1772x; 1.1772x over previous
//
#include <hip/hip_runtime.h>
#include <stdint.h>

// ---------------- types ----------------
typedef short shortx8 __attribute__((ext_vector_type(8)));
typedef float floatx4 __attribute__((ext_vector_type(4)));

#define T_LEN 2048
#define BATCH 16
#define DMODEL 512
#define HDIM 512
#define M_ROWS (T_LEN * BATCH)          // 32768
#define NCHUNK 32
#define LCHUNK 64                        // T per chunk
#define NCHAIN (BATCH * HDIM)            // 8192
#define Y_ELEMS (M_ROWS * DMODEL)        // 16777216

// ---------------- helpers ----------------
__device__ __forceinline__ unsigned short f2bf(float f) {
    union { float f; unsigned u; } v; v.f = f;
    unsigned r = (v.u + 0x7FFFu + ((v.u >> 16) & 1u)) >> 16;
    return (unsigned short)r;
}
__device__ __forceinline__ float bf2f(unsigned short u) {
    union { unsigned u; float f; } v; v.u = ((unsigned)u) << 16;
    return v.f;
}

// ---------------- merged prep + operand conversion + x cast ----------------
// blocks 0..16383:      x fp32 -> bf16 cast (float4/ushort4 vectorized)
// blocks 16384..20479:  Bs/C2 conversion (interleaved cols: n=2h -> re, 2h+1 -> im)
// block 20480:          per-channel lam, lam^64 (double precision)
__global__ void conv_all(const float4* __restrict__ x4, unsigned short* __restrict__ xb,
                         const float* __restrict__ B_re, const float* __restrict__ B_im,
                         const float* __restrict__ nu_log, const float* __restrict__ th_log,
                         const float* __restrict__ C_re, const float* __restrict__ C_im,
                         unsigned short* __restrict__ Bs, unsigned short* __restrict__ C2,
                         float* lam_re, float* lam_im, float* l64_re, float* l64_im) {
    int bid = blockIdx.x;
    int tid = threadIdx.x;
    if (bid < 16384) {
        int i = bid * 256 + tid;         // 0 .. Y_ELEMS/4-1
        float4 v = x4[i];
        ushort4 u;
        u.x = f2bf(v.x); u.y = f2bf(v.y); u.z = f2bf(v.z); u.w = f2bf(v.w);
        *(ushort4*)(xb + (size_t)i * 4) = u;
    } else if (bid < 20480) {
        int idx = (bid - 16384) * 256 + tid;   // 0 .. 1M-1
        if (idx < 524288) {
            int n = idx >> 9;            // row 0..1023
            int d = idx & 511;
            int h = n >> 1;
            float g = sqrtf(1.0f - expf(-2.0f * expf(nu_log[h])));
            float v = ((n & 1) ? B_im[h * DMODEL + d] : B_re[h * DMODEL + d]) * g;
            Bs[idx] = f2bf(v);
        } else {
            int i2 = idx - 524288;
            int d = i2 >> 10;            // /1024
            int k = i2 & 1023;
            int h = k >> 1;
            float v = (k & 1) ? -C_im[d * HDIM + h] : C_re[d * HDIM + h];
            C2[i2] = f2bf(v);
        }
    } else {
        for (int h = tid; h < HDIM; h += 256) {
            double nu  = exp((double)nu_log[h]);
            double th  = exp((double)th_log[h]);
            double mag = exp(-nu);
            double lre = mag * cos(th), lim = mag * sin(th);
            double zr = lre, zi = lim;
            for (int i = 0; i < 6; ++i) { double nr = zr*zr - zi*zi; zi = 2.0*zr*zi; zr = nr; }
            lam_re[h] = (float)lre; lam_im[h] = (float)lim;
            l64_re[h] = (float)zr;  l64_im[h] = (float)zi;
        }
    }
}

// ---------------- NT GEMM, 128x128 tile, BK=64, bf16 MFMA 16x16x32 ----------------
// __launch_bounds__(256, 4): R7 post-mortem — min-waves=5 capped the unified
// VGPR/AGPR budget at 102/wave vs the ~128 this kernel needs (64 arch + 64 acc)
// -> VGPR_Count 48 + scratch spills (+26MB WRITE_SIZE/dispatch), 43.5->69us.
// 4 blocks/CU = 128 regs/wave budget = exact fit; known-good 43.5us.
// A: M x K row-major bf16.  Bmat: N x K row-major bf16.  D[m][n] = sum_k A[m][k]*Bmat[n][k]
// LDS tiles 128x64 with XOR-swizzled 16B column chunks (c16 ^= r&7).
// MODE 0: OutB[m*N+n] = bf16(acc)
// MODE 1: OutF[m*N+n] = acc + Dv[n]*bf2f(Xb[m*N+n])
template <int MODE>
__global__ __launch_bounds__(256, 4) void gemm_nt(const unsigned short* __restrict__ A,
                                                  const unsigned short* __restrict__ Bmat,
                                                  const int K, const int N, const int lgNB,
                                                  unsigned short* __restrict__ OutB,
                                                  float* __restrict__ OutF,
                                                  const float* __restrict__ Dv,
                                                  const unsigned short* __restrict__ Xb) {
    __shared__ unsigned short As[128 * 64];
    __shared__ unsigned short Bs[128 * 64];
    const int L = blockIdx.x;
    const int xcd = L & 7;
    const int slot = L >> 3;
    const int bn = slot & ((1 << lgNB) - 1);
    const int bm = xcd * 32 + (slot >> lgNB);
    const int tid = threadIdx.x;
    const int wv = tid >> 6, lane = tid & 63;
    const int wr = wv >> 1, wc = wv & 1;
    const int lrow = lane & 15, qq = lane >> 4;
    floatx4 acc[4][4] = {};

    const size_t rowA = (size_t)bm * 128, rowB = (size_t)bn * 128;
    for (int k0 = 0; k0 < K; k0 += 64) {
        #pragma unroll
        for (int j = 0; j < 4; ++j) {
            int ch  = j * 256 + wv * 64 + lane;            // 0..1023
            int r   = ch >> 3;                             // row 0..127
            int c16 = ch & 7;                              // LDS 16B-col
            int g16 = c16 ^ (r & 7);                       // swizzled global 16B-col
            const unsigned short* ga = A    + (rowA + r) * (size_t)K + (k0 + g16 * 8);
            const unsigned short* gb = Bmat + (rowB + r) * (size_t)K + (k0 + g16 * 8);
            unsigned short* la = As + (size_t)(j * 256 + wv * 64) * 8;   // wave-uniform base
            unsigned short* lb = Bs + (size_t)(j * 256 + wv * 64) * 8;
            __builtin_amdgcn_global_load_lds((const __attribute__((address_space(1))) void*)ga,
                                             (__attribute__((address_space(3))) void*)la, 16, 0, 0);
            __builtin_amdgcn_global_load_lds((const __attribute__((address_space(1))) void*)gb,
                                             (__attribute__((address_space(3))) void*)lb, 16, 0, 0);
        }
        __syncthreads();
        #pragma unroll
        for (int s = 0; s < 2; ++s) {                      // two k-substeps of 32
            shortx8 af[4], bf[4];
            #pragma unroll
            for (int mi = 0; mi < 4; ++mi) {
                int row = wr * 64 + mi * 16 + lrow;
                int c16 = (s * 4 + qq) ^ (row & 7);
                af[mi] = *(const shortx8*)&As[row * 64 + c16 * 8];
            }
            #pragma unroll
            for (int ni = 0; ni < 4; ++ni) {
                int row = wc * 64 + ni * 16 + lrow;
                int c16 = (s * 4 + qq) ^ (row & 7);
                bf[ni] = *(const shortx8*)&Bs[row * 64 + c16 * 8];
            }
            #pragma unroll
            for (int mi = 0; mi < 4; ++mi)
                #pragma unroll
                for (int ni = 0; ni < 4; ++ni)
                    acc[mi][ni] = __builtin_amdgcn_mfma_f32_16x16x32_bf16(af[mi], bf[ni], acc[mi][ni], 0, 0, 0);
        }
        __syncthreads();
    }

    // epilogue: D row = qq*4 + r, col = lrow   (m89/m91-verified C/D mapping)
    #pragma unroll
    for (int mi = 0; mi < 4; ++mi) {
        int mbase = bm * 128 + wr * 64 + mi * 16 + qq * 4;
        #pragma unroll
        for (int ni = 0; ni < 4; ++ni) {
            int n = bn * 128 + wc * 64 + ni * 16 + lrow;
            if (MODE == 0) {
                #pragma unroll
                for (int r = 0; r < 4; ++r)
                    OutB[(size_t)(mbase + r) * N + n] = f2bf(acc[mi][ni][r]);
            } else {
                float dv = Dv[n];
                #pragma unroll
                for (int r = 0; r < 4; ++r) {
                    size_t idx = (size_t)(mbase + r) * N + n;
                    OutF[idx] = acc[mi][ni][r] + dv * bf2f(Xb[idx]);
                }
            }
        }
    }
}

// ---------------- scan pass 1: per-chunk partial (zero init), 1 channel/thread ----
// Interleaved Bu layout: channel h of row m lives at shorts (2h, 2h+1) ->
// one 4B load per step yields (re,im).  Chunk 31's partial is never consumed
// by scan_apply (carries only for k < chunk) -> grid covers chunks 0..30.
__global__ void scan_partial(const unsigned short* __restrict__ Bu,
                             const float* __restrict__ lam_re, const float* __restrict__ lam_im,
                             float2* __restrict__ car) {
    int gid = blockIdx.x * blockDim.x + threadIdx.x;     // 0 .. 31*8192-1
    int chunk = gid >> 13;           // block-uniform (8192 = 32 blocks of 256)
    int idx = gid & 8191;            // chain = b*512 + h
    int b = idx >> 9, h = idx & 511;
    float lr = lam_re[h], li = lam_im[h];
    float vr = 0.f, vi = 0.f;
    const unsigned short* p = Bu + (size_t)chunk * LCHUNK * BATCH * 1024 + (size_t)b * 1024 + 2 * h;
    #pragma unroll 4
    for (int j = 0; j < LCHUNK; ++j) {
        unsigned w = *(const unsigned*)p;
        float br = bf2f((unsigned short)w), bi = bf2f((unsigned short)(w >> 16));
        float nr = lr * vr - li * vi + br;
        float ni = lr * vi + li * vr + bi;
        vr = nr; vi = ni;
        p += BATCH * 1024;
    }
    car[chunk * NCHAIN + idx] = make_float2(vr, vi);
}

// ---------------- scan pass 2 (fused combine+apply), 1 channel/thread ----------
__global__ void scan_apply(unsigned short* __restrict__ Bu,
                           const float* __restrict__ lam_re, const float* __restrict__ lam_im,
                           const float* __restrict__ l64_re, const float* __restrict__ l64_im,
                           const float* __restrict__ h0_re, const float* __restrict__ h0_im,
                           const float2* __restrict__ car,
                           float* __restrict__ out_final, int interleave) {
    int gid = blockIdx.x * blockDim.x + threadIdx.x;
    int chunk = gid >> 13;           // block-uniform
    int idx = gid & 8191;            // chain = b*512 + h
    int b = idx >> 9, h = idx & 511;
    // carry-in: h0 advanced through preceding chunks via lam^64
    float Lr = l64_re[h], Li = l64_im[h];
    float vr = h0_re[idx], vi = h0_im[idx];
    for (int k = 0; k < chunk; ++k) {
        float2 cv = car[k * NCHAIN + idx];
        float nr = Lr * vr - Li * vi + cv.x;
        float ni = Lr * vi + Li * vr + cv.y;
        vr = nr; vi = ni;
    }
    // main 64-step streaming recurrence, h overwrites Bu in-place
    float lr = lam_re[h], li = lam_im[h];
    unsigned short* p = Bu + (size_t)chunk * LCHUNK * BATCH * 1024 + (size_t)b * 1024 + 2 * h;
    #pragma unroll 4
    for (int j = 0; j < LCHUNK; ++j) {
        unsigned w = *(const unsigned*)p;
        float br = bf2f((unsigned short)w), bi = bf2f((unsigned short)(w >> 16));
        float nr = lr * vr - li * vi + br;
        float ni = lr * vi + li * vr + bi;
        vr = nr; vi = ni;
        *(unsigned*)p = (unsigned)f2bf(vr) | ((unsigned)f2bf(vi) << 16);
        p += BATCH * 1024;
    }
    if (chunk == NCHUNK - 1) {       // final_state = h[T-1]
        if (interleave) {
            out_final[2 * idx]     = vr;
            out_final[2 * idx + 1] = vi;
        } else {
            out_final[idx] = vr;
        }
    }
}

// ---------------- launch ----------------
extern "C" void kernel_launch(void* const* d_in, const int* in_sizes, int n_in,
                              void* d_out, int out_size, void* d_ws, size_t ws_size,
                              hipStream_t stream) {
    const float* x        = (const float*)d_in[0];
    const float* h0_re    = (const float*)d_in[1];
    const float* h0_im    = (const float*)d_in[2];
    const float* nu_log   = (const float*)d_in[3];
    const float* theta_lg = (const float*)d_in[4];
    const float* B_re     = (const float*)d_in[5];
    const float* B_im     = (const float*)d_in[6];
    const float* C_re     = (const float*)d_in[7];
    const float* C_im     = (const float*)d_in[8];
    const float* D_vec    = (const float*)d_in[9];

    // workspace layout (~105 MB total)
    char* ws = (char*)d_ws;
    unsigned short* BuH  = (unsigned short*)(ws + 0);              // 64 MB  (M x 1024 bf16): Bu, then h in-place
    unsigned short* xb   = (unsigned short*)(ws + 67108864);       // 32 MB  (M x 512 bf16)
    unsigned short* Bs   = (unsigned short*)(ws + 100663296);      // 1 MB   (1024 x 512 bf16)
    unsigned short* C2   = (unsigned short*)(ws + 101711872);      // 1 MB   (512 x 1024 bf16)
    float2* car          = (float2*)(ws + 102760448);              // 2 MB   (32 x 8192 float2)
    float* lam_re        = (float*)(ws + 104857600);
    float* lam_im        = (float*)(ws + 104859648);
    float* l64_re        = (float*)(ws + 104861696);
    float* l64_im        = (float*)(ws + 104863744);

    // adaptive d_out layout: out_size = Y_ELEMS + {16384 interleaved | 8192 real-only}
    int fs_elems = out_size - Y_ELEMS;
    int interleave = (fs_elems == 8192) ? 0 : 1;
    if (fs_elems != 8192) fs_elems = 16384;
    float* out_final = (float*)d_out;
    float* y_out     = (float*)d_out + fs_elems;

    // 1. merged x-cast + operand conversions + channel constants (one launch)
    conv_all<<<20481, 256, 0, stream>>>((const float4*)x, xb,
                                        B_re, B_im, nu_log, theta_lg, C_re, C_im,
                                        Bs, C2, lam_re, lam_im, l64_re, l64_im);
    // 2. GEMM1: Bu = xb (M x 512) . Bs^T (1024 x 512) -> M x 1024 bf16 (interleaved cols)
    gemm_nt<0><<<2048, 256, 0, stream>>>(xb, Bs, DMODEL, 1024, 3, BuH, nullptr, nullptr, nullptr);
    // 3. chunked scan over T (partial for chunks 0..30 -> fused prefix+apply in-place)
    scan_partial<<<((NCHUNK - 1) * NCHAIN) / 256, 256, 0, stream>>>(BuH, lam_re, lam_im, car);
    scan_apply<<<(NCHUNK * NCHAIN) / 256, 256, 0, stream>>>(BuH, lam_re, lam_im, l64_re, l64_im,
                                                            h0_re, h0_im, car,
                                                            out_final, interleave);
    // 4. GEMM2: y = h (M x 1024) . C2^T (512 x 1024) + Dv*xb -> M x 512 fp32
    gemm_nt<1><<<1024, 256, 0, stream>>>(BuH, C2, 1024, 512, 2, nullptr, y_out, D_vec, xb);
}